// Round 2
// baseline (357.212 us; speedup 1.0000x reference)
//
#include <hip/hip_runtime.h>
#include <math.h>

// Problem constants (hardcoded from reference: CHILD_SPACE=12, K=3, S=1,
// CHILD_CAPS=16, PARENT_CAPS=32, POSE=16, N=4 -> P=10)
#define NB     4
#define P      10
#define P2     100
#define CS     12
#define KKSL   9      // kernel slots (3x3)
#define CCAPS  16
#define KTOT   144    // KKSL*CCAPS
#define O      32
#define CH     16
#define EPSF   1e-9f
#define LNF    22.2222222222222222f   // 100/(144/32)
#define TWO_PI 6.28318530717958647f

#define RRN (NB*P2*KTOT*O)   // 1,843,200 floats

__device__ float g_rr[RRN];
__device__ float g_zz[RRN];

// number of parents covering child coordinate x (1-D): min(x+1, 3, 12-x)
__device__ __forceinline__ int npar(int x) {
    int a = x + 1;
    int b = CS - x;
    int m = a < 3 ? a : 3;
    return m < b ? m : b;
}

#define SHFL_SUM16(x) { x += __shfl_xor(x,1); x += __shfl_xor(x,2); \
                        x += __shfl_xor(x,4); x += __shfl_xor(x,8); }
#define SHFL_SUM32(x) { x += __shfl_xor(x,1); x += __shfl_xor(x,2); \
                        x += __shfl_xor(x,4); x += __shfl_xor(x,8); \
                        x += __shfl_xor(x,16); }
#define SHFL_MAX32(x) { x = fmaxf(x, __shfl_xor(x,1)); x = fmaxf(x, __shfl_xor(x,2)); \
                        x = fmaxf(x, __shfl_xor(x,4)); x = fmaxf(x, __shfl_xor(x,8)); \
                        x = fmaxf(x, __shfl_xor(x,16)); }

// One block per (b, parent). 512 threads = (o, ch), ch fastest.
// Does m_step; if !LAST also computes zz (= log(act)+o_p0+o_p2) for the
// following e_step. If LAST writes poses + activations to out.
template<bool FIRST, bool LAST>
__global__ __launch_bounds__(512)
void mstep_kernel(const float* __restrict__ votes,
                  const float* __restrict__ acts,
                  const float* __restrict__ beta_v,
                  const float* __restrict__ beta_a,
                  float* __restrict__ out,
                  float lam)
{
    __shared__ float rrp[KTOT * 33];   // rr' = rr * act_i, stride 33 (pad)
    __shared__ float act_lds[KTOT];
    __shared__ float cost_lds[O];

    const int tid = threadIdx.x;
    const int bp  = blockIdx.x;          // b*100 + p
    const int p   = bp % P2;
    const int pr  = p / P, pc = p % P;
    const int o   = tid >> 4;
    const int ch  = tid & 15;

    // stage child activations
    for (int i = tid; i < KTOT; i += 512)
        act_lds[i] = acts[bp * KTOT + i];
    __syncthreads();

    // stage rr' = rr * act
    for (int i = tid; i < KTOT * O; i += 512) {
        int k  = i >> 5;      // kidx = kslot*16 + cc
        int oo = i & 31;
        float r;
        if (FIRST) {
            int kslot = k >> 4;
            int kr = kslot / 3, kc = kslot % 3;
            float ppc = (float)(npar(pr + kr) * npar(pc + kc));
            r = 1.0f / (ppc * (float)O + EPSF);
        } else {
            r = g_rr[(size_t)bp * (KTOT * O) + i];
        }
        rrp[k * 33 + oo] = r * act_lds[k];
    }
    __syncthreads();

    // main pass: weighted sums over K
    const float* vb = votes + (size_t)bp * (KTOT * O * CH);
    float s = 0.f, m1 = 0.f, m2 = 0.f;
    #pragma unroll 4
    for (int k = 0; k < KTOT; ++k) {
        float rp = rrp[k * 33 + o];          // broadcast within ch-group
        float v  = vb[k * 512 + tid];
        s  += rp;
        m1 += rp * v;
        m2 += rp * v * v;
    }
    float denom = s + EPSF;
    float mean  = m1 / denom;
    float var   = m2 / denom - mean * mean;
    if (var < 1e-30f) var = 1e-30f;

    // cost: per (o): sum_ch (beta_v + 0.5*log(var+eps)) * S * LNF
    float lv = logf(var + EPSF);
    float sum_lv = lv;
    SHFL_SUM16(sum_lv);
    float bv = beta_v[o];
    float cost_o = (16.f * bv + 0.5f * sum_lv) * s * LNF;

    if (ch == 0) cost_lds[o] = cost_o;
    __syncthreads();
    float cm = 0.f;
    #pragma unroll
    for (int i = 0; i < O; ++i) cm += cost_lds[i];
    cm *= (1.0f / (float)O);
    float sq = 0.f;
    #pragma unroll
    for (int i = 0; i < O; ++i) { float d = cost_lds[i] - cm; sq += d * d; }
    float cstd = sqrtf(sq * (1.0f / (float)O));

    float ba = beta_a[o];
    float act_j = 1.0f / (1.0f + expf(-lam * (ba + (cm - cost_o) / (cstd + EPSF))));

    if (LAST) {
        // poses: (b,p,o,ch) contiguous = bp*512 + tid
        out[(size_t)bp * 512 + tid] = mean;
        if (ch == 0)
            out[(size_t)NB * P2 * O * CH + bp * O + o] = act_j;
        return;
    }

    // zz pass: zz[k,o] = log(act_j+eps) + o_p2[o] - sum_ch (v-mean)^2/(2 var)
    float i2v = 0.5f / var;
    float l2 = logf(TWO_PI * var);
    float sum_l2 = l2;
    SHFL_SUM16(sum_l2);
    float zpre = logf(act_j + EPSF) - 0.5f * sum_l2;

    float* zzb = g_zz + (size_t)bp * (KTOT * O);
    for (int k = 0; k < KTOT; ++k) {
        float v = vb[k * 512 + tid];
        float d = v - mean;
        float t = d * d * i2v;
        SHFL_SUM16(t);                        // sum over ch (all lanes get it)
        if (ch == 0) zzb[k * 32 + o] = zpre - t;
    }
}

// e_step finish: segment softmax over (parents covering child, O).
// One block per (b, child) = 4*144. 512 threads = (cc, o), o fastest.
__global__ __launch_bounds__(512)
void estep_kernel()
{
    const int tid = threadIdx.x;
    const int bc  = blockIdx.x;           // b*144 + c
    const int b   = bc / (CS * CS);
    const int c   = bc % (CS * CS);
    const int cr  = c / CS, cl = c % CS;
    const int cc  = tid >> 5;
    const int o   = tid & 31;

    float vals[9];
    float vmax = -1e30f;
    #pragma unroll
    for (int kr = 0; kr < 3; ++kr) {
        int pr = cr - kr;
        #pragma unroll
        for (int kc = 0; kc < 3; ++kc) {
            int pc = cl - kc;
            float v = -1e30f;
            if (pr >= 0 && pr <= 9 && pc >= 0 && pc <= 9) {
                int pp = pr * P + pc;
                int kslot = kr * 3 + kc;
                size_t idx = ((size_t)(b * P2 + pp) * KTOT + kslot * CCAPS + cc) * O + o;
                v = g_zz[idx];
            }
            vals[kr * 3 + kc] = v;
            vmax = fmaxf(vmax, v);
        }
    }
    SHFL_MAX32(vmax);            // max over o lanes (per cc)

    float psum = 0.f;
    #pragma unroll
    for (int i = 0; i < 9; ++i) {
        float e = (vals[i] > -1e29f) ? expf(vals[i] - vmax) : 0.f;
        vals[i] = e;
        psum += e;
    }
    SHFL_SUM32(psum);            // sum over o lanes; parents already summed in vals loop
    float inv = 1.0f / psum;

    #pragma unroll
    for (int kr = 0; kr < 3; ++kr) {
        int pr = cr - kr;
        #pragma unroll
        for (int kc = 0; kc < 3; ++kc) {
            int pc = cl - kc;
            if (pr >= 0 && pr <= 9 && pc >= 0 && pc <= 9) {
                int pp = pr * P + pc;
                int kslot = kr * 3 + kc;
                size_t idx = ((size_t)(b * P2 + pp) * KTOT + kslot * CCAPS + cc) * O + o;
                g_rr[idx] = vals[kr * 3 + kc] * inv;
            }
        }
    }
}

extern "C" void kernel_launch(void* const* d_in, const int* in_sizes, int n_in,
                              void* d_out, int out_size, void* d_ws, size_t ws_size,
                              hipStream_t stream)
{
    (void)in_sizes; (void)n_in; (void)out_size; (void)d_ws; (void)ws_size;

    const float* votes = (const float*)d_in[0];
    const float* acts  = (const float*)d_in[1];
    const float* bv    = (const float*)d_in[2];
    const float* ba    = (const float*)d_in[3];
    float* out = (float*)d_out;

    const float lam0 = 0.01f * (1.0f - 0.95f);
    const float lam1 = 0.01f * (1.0f - 0.95f * 0.95f);
    const float lam2 = 0.01f * (1.0f - 0.95f * 0.95f * 0.95f);

    dim3 blk(512);
    mstep_kernel<true,  false><<<dim3(NB * P2), blk, 0, stream>>>(votes, acts, bv, ba, out, lam0);
    estep_kernel<<<dim3(NB * CS * CS), blk, 0, stream>>>();
    mstep_kernel<false, false><<<dim3(NB * P2), blk, 0, stream>>>(votes, acts, bv, ba, out, lam1);
    estep_kernel<<<dim3(NB * CS * CS), blk, 0, stream>>>();
    mstep_kernel<false, true ><<<dim3(NB * P2), blk, 0, stream>>>(votes, acts, bv, ba, out, lam2);
}

// Round 3
// 267.885 us; speedup vs baseline: 1.3335x; 1.3335x over previous
//
#include <hip/hip_runtime.h>
#include <math.h>

// EM routing, hardcoded geometry: CHILD_SPACE=12, K=3, S=1 -> P=10,
// CHILD_CAPS=16, PARENT_CAPS=O=32, POSE=16, N=4, KTOT=144
#define NB     4
#define P      10
#define P2     100
#define CS     12
#define CCAPS  16
#define KTOT   144
#define O      32
#define POSE   16
#define EPSF   1e-9f
#define LNF    22.2222222222222222f   // 100/(144/32)
#define LOG2PI 1.83787706640934548f

#define RRN (NB*P2*KTOT*O)   // 1,843,200 floats

__device__ float g_rr[RRN];
__device__ float g_zz[RRN];

// number of parents covering child coordinate x (1-D): min(x+1, 3, 12-x)
__device__ __forceinline__ int npar(int x) {
    int a = x + 1, b = CS - x;
    int m = a < 3 ? a : 3;
    return m < b ? m : b;
}

// One block per (b, parent). 512 threads: tid = kq*128 + q, kq in [0,4) splits
// K; q = o*4 + c4 where thread owns pose components c4*4..c4*4+3 (float4).
template<bool FIRST, bool LAST>
__global__ __launch_bounds__(512)
void mstep_kernel(const float* __restrict__ votes,
                  const float* __restrict__ acts,
                  const float* __restrict__ beta_v,
                  const float* __restrict__ beta_a,
                  float* __restrict__ out, float lam)
{
    __shared__ __align__(16) float rr_lds[KTOT * O];  // 18432 B; aliased later
    __shared__ float act_lds[KTOT];
    __shared__ __align__(16) float mean_lds[512];
    __shared__ __align__(16) float i2v_lds[512];
    __shared__ float cost_lds[O];
    __shared__ float slv_lds[O];
    __shared__ float zpre_lds[O];
    __shared__ float actj_lds[O];

    const int tid = threadIdx.x;
    const int kq  = tid >> 7;
    const int q   = tid & 127;
    const int o   = q >> 2;
    const int c4  = q & 3;
    const int bp  = blockIdx.x;
    const int p   = bp % P2;
    const int pr  = p / P, pc = p % P;

    // 1. child activations
    if (tid < KTOT) act_lds[tid] = acts[bp * KTOT + tid];
    __syncthreads();

    // 2. stage rr' = rr * act into LDS, layout [k][o] (stride 32)
    if (FIRST) {
        for (int f = tid; f < KTOT * O / 4; f += 512) {
            int k = f >> 3;
            int kslot = k >> 4;
            int kr = kslot / 3, kc = kslot % 3;
            float ppc = (float)(npar(pr + kr) * npar(pc + kc));
            float r = act_lds[k] / (ppc * 32.0f + EPSF);
            ((float4*)rr_lds)[f] = make_float4(r, r, r, r);
        }
    } else {
        const float4* src = (const float4*)(g_rr + (size_t)bp * (KTOT * O));
        for (int f = tid; f < KTOT * O / 4; f += 512) {
            float4 r4 = src[f];
            float a = act_lds[f >> 3];
            r4.x *= a; r4.y *= a; r4.z *= a; r4.w *= a;
            ((float4*)rr_lds)[f] = r4;
        }
    }
    __syncthreads();

    // 3. main pass: s, m1, m2 (each thread: 36 float4 loads)
    const float* vb = votes + (size_t)bp * (KTOT * O * POSE);
    float  s  = 0.f;
    float4 m1 = make_float4(0.f, 0.f, 0.f, 0.f);
    float4 m2 = make_float4(0.f, 0.f, 0.f, 0.f);
    #pragma unroll 4
    for (int k = kq; k < KTOT; k += 4) {
        float  rp = rr_lds[k * O + o];            // wave-uniform k, 16 addrs -> bcast
        float4 v  = *(const float4*)(vb + k * 512 + q * 4);
        s += rp;
        m1.x += rp * v.x;       m1.y += rp * v.y;
        m1.z += rp * v.z;       m1.w += rp * v.w;
        m2.x += rp * v.x * v.x; m2.y += rp * v.y * v.y;
        m2.z += rp * v.z * v.z; m2.w += rp * v.w * v.w;
    }
    __syncthreads();   // everyone done reading rr_lds

    // 4. alias partial-sum arrays onto rr_lds (exactly 4608 floats)
    float4* lm1 = (float4*)rr_lds;            // [512]
    float4* lm2 = (float4*)(rr_lds + 2048);   // [512]
    float*  lss = rr_lds + 4096;              // [512]
    lm1[tid] = m1; lm2[tid] = m2; lss[tid] = s;
    __syncthreads();

    // 5. reduce over kq on tid<128; mean/var; per-o cost
    if (tid < 128) {
        float4 a, b;
        a = lm1[tid];        b = lm1[128 + tid];
        m1.x = a.x + b.x; m1.y = a.y + b.y; m1.z = a.z + b.z; m1.w = a.w + b.w;
        a = lm1[256 + tid];  b = lm1[384 + tid];
        m1.x += a.x + b.x; m1.y += a.y + b.y; m1.z += a.z + b.z; m1.w += a.w + b.w;
        a = lm2[tid];        b = lm2[128 + tid];
        m2.x = a.x + b.x; m2.y = a.y + b.y; m2.z = a.z + b.z; m2.w = a.w + b.w;
        a = lm2[256 + tid];  b = lm2[384 + tid];
        m2.x += a.x + b.x; m2.y += a.y + b.y; m2.z += a.z + b.z; m2.w += a.w + b.w;
        s = lss[tid] + lss[128 + tid] + lss[256 + tid] + lss[384 + tid];

        float denom = s + EPSF;
        float4 mean, var, i2;
        mean.x = m1.x / denom; mean.y = m1.y / denom;
        mean.z = m1.z / denom; mean.w = m1.w / denom;
        var.x = m2.x / denom - mean.x * mean.x;
        var.y = m2.y / denom - mean.y * mean.y;
        var.z = m2.z / denom - mean.z * mean.z;
        var.w = m2.w / denom - mean.w * mean.w;
        var.x = fmaxf(var.x, 1e-30f); var.y = fmaxf(var.y, 1e-30f);
        var.z = fmaxf(var.z, 1e-30f); var.w = fmaxf(var.w, 1e-30f);
        i2.x = 0.5f / var.x; i2.y = 0.5f / var.y;
        i2.z = 0.5f / var.z; i2.w = 0.5f / var.w;
        ((float4*)mean_lds)[tid] = mean;
        ((float4*)i2v_lds)[tid]  = i2;

        float lv = logf(var.x + EPSF) + logf(var.y + EPSF)
                 + logf(var.z + EPSF) + logf(var.w + EPSF);
        float slv = lv;
        slv += __shfl_xor(slv, 1);
        slv += __shfl_xor(slv, 2);       // sum over 16 pose comps (4 c4-lanes)
        if (c4 == 0) {
            cost_lds[o] = (16.f * beta_v[o] + 0.5f * slv) * s * LNF;
            slv_lds[o]  = slv;
        }
    }
    __syncthreads();

    // 6. cost mean/std over o -> act_j, zpre
    if (tid < 128) {
        float cm = 0.f;
        #pragma unroll
        for (int i = 0; i < O; ++i) cm += cost_lds[i];
        cm *= (1.0f / 32.0f);
        float sq = 0.f;
        #pragma unroll
        for (int i = 0; i < O; ++i) { float d = cost_lds[i] - cm; sq += d * d; }
        float cstd = sqrtf(sq * (1.0f / 32.0f));
        float aj = 1.f / (1.f + expf(-lam * (beta_a[o] + (cm - cost_lds[o]) / (cstd + EPSF))));
        if (c4 == 0) {
            actj_lds[o] = aj;
            zpre_lds[o] = logf(aj + EPSF) - 0.5f * (16.f * LOG2PI + slv_lds[o]);
        }
    }
    __syncthreads();

    if (LAST) {
        // poses: (b,p,o,pose) = bp*512 + q*4 (float4); acts after all poses
        if (tid < 128)
            ((float4*)out)[bp * 128 + tid] = ((float4*)mean_lds)[tid];
        if (tid < O)
            out[(size_t)NB * P2 * 512 + bp * O + tid] = actj_lds[tid];
        return;
    }

    // 7. zz pass: zz[k,o] = zpre[o] - sum_pose (v-mean)^2/(2 var)
    {
        float4 mean = ((float4*)mean_lds)[q];
        float4 i2   = ((float4*)i2v_lds)[q];
        float  zp   = zpre_lds[o];
        float* zzb  = g_zz + (size_t)bp * (KTOT * O);
        #pragma unroll 4
        for (int k = kq; k < KTOT; k += 4) {
            float4 v = *(const float4*)(vb + k * 512 + q * 4);
            float dx = v.x - mean.x, dy = v.y - mean.y;
            float dz = v.z - mean.z, dw = v.w - mean.w;
            float t = dx * dx * i2.x + dy * dy * i2.y + dz * dz * i2.z + dw * dw * i2.w;
            t += __shfl_xor(t, 1);
            t += __shfl_xor(t, 2);       // sum over 16 pose comps
            if (c4 == 0) zzb[k * O + o] = zp - t;
        }
    }
}

// e_step finish: segment softmax over (parents covering child, O).
// One block per (b, child) = 4*144. 512 threads = (cc, o), o fastest.
__global__ __launch_bounds__(512)
void estep_kernel()
{
    const int tid = threadIdx.x;
    const int bc  = blockIdx.x;           // b*144 + c
    const int b   = bc / (CS * CS);
    const int c   = bc % (CS * CS);
    const int cr  = c / CS, cl = c % CS;
    const int cc  = tid >> 5;
    const int o   = tid & 31;

    float vals[9];
    float vmax = -1e30f;
    #pragma unroll
    for (int kr = 0; kr < 3; ++kr) {
        int pr = cr - kr;
        #pragma unroll
        for (int kc = 0; kc < 3; ++kc) {
            int pc = cl - kc;
            float v = -1e30f;
            if (pr >= 0 && pr <= 9 && pc >= 0 && pc <= 9) {
                int pp = pr * P + pc;
                int kslot = kr * 3 + kc;
                size_t idx = ((size_t)(b * P2 + pp) * KTOT + kslot * CCAPS + cc) * O + o;
                v = g_zz[idx];
            }
            vals[kr * 3 + kc] = v;
            vmax = fmaxf(vmax, v);
        }
    }
    vmax = fmaxf(vmax, __shfl_xor(vmax, 1));
    vmax = fmaxf(vmax, __shfl_xor(vmax, 2));
    vmax = fmaxf(vmax, __shfl_xor(vmax, 4));
    vmax = fmaxf(vmax, __shfl_xor(vmax, 8));
    vmax = fmaxf(vmax, __shfl_xor(vmax, 16));   // max over o lanes (per cc)

    float psum = 0.f;
    #pragma unroll
    for (int i = 0; i < 9; ++i) {
        float e = (vals[i] > -1e29f) ? expf(vals[i] - vmax) : 0.f;
        vals[i] = e;
        psum += e;
    }
    psum += __shfl_xor(psum, 1);
    psum += __shfl_xor(psum, 2);
    psum += __shfl_xor(psum, 4);
    psum += __shfl_xor(psum, 8);
    psum += __shfl_xor(psum, 16);               // sum over o lanes
    float inv = 1.0f / psum;

    #pragma unroll
    for (int kr = 0; kr < 3; ++kr) {
        int pr = cr - kr;
        #pragma unroll
        for (int kc = 0; kc < 3; ++kc) {
            int pc = cl - kc;
            if (pr >= 0 && pr <= 9 && pc >= 0 && pc <= 9) {
                int pp = pr * P + pc;
                int kslot = kr * 3 + kc;
                size_t idx = ((size_t)(b * P2 + pp) * KTOT + kslot * CCAPS + cc) * O + o;
                g_rr[idx] = vals[kr * 3 + kc] * inv;
            }
        }
    }
}

extern "C" void kernel_launch(void* const* d_in, const int* in_sizes, int n_in,
                              void* d_out, int out_size, void* d_ws, size_t ws_size,
                              hipStream_t stream)
{
    (void)in_sizes; (void)n_in; (void)out_size; (void)d_ws; (void)ws_size;

    const float* votes = (const float*)d_in[0];
    const float* acts  = (const float*)d_in[1];
    const float* bv    = (const float*)d_in[2];
    const float* ba    = (const float*)d_in[3];
    float* out = (float*)d_out;

    const float lam0 = 0.01f * (1.0f - 0.95f);
    const float lam1 = 0.01f * (1.0f - 0.95f * 0.95f);
    const float lam2 = 0.01f * (1.0f - 0.95f * 0.95f * 0.95f);

    dim3 blk(512);
    mstep_kernel<true,  false><<<dim3(NB * P2), blk, 0, stream>>>(votes, acts, bv, ba, out, lam0);
    estep_kernel<<<dim3(NB * CS * CS), blk, 0, stream>>>();
    mstep_kernel<false, false><<<dim3(NB * P2), blk, 0, stream>>>(votes, acts, bv, ba, out, lam1);
    estep_kernel<<<dim3(NB * CS * CS), blk, 0, stream>>>();
    mstep_kernel<false, true ><<<dim3(NB * P2), blk, 0, stream>>>(votes, acts, bv, ba, out, lam2);
}